// Round 5
// baseline (292.021 us; speedup 1.0000x reference)
//
#include <hip/hip_runtime.h>
#include <hip/hip_cooperative_groups.h>

namespace cg = cooperative_groups;

#define S_DIM 256
#define B_DIM 64
#define IN_DIM 3
#define H_DIM 128
#define N_NODES 1000000
#define P_INF 8
#define P_OUTF 32
#define NUM_GRAPHS 64
#define EPSF 1e-6f

// d_out float offsets
#define OUT_OUTPUTS 0
#define OUT_HIDDEN (S_DIM * B_DIM * H_DIM)            // 2097152
#define OUT_LG (OUT_HIDDEN + B_DIM * H_DIM)           // 2105344

// geometry: single cooperative dispatch
#define NBLK 1024
#define RPB 977            // 1024*977 = 1,000,448 >= 1e6
#define RPW 245            // rows per wave (4 waves: 980 >= 977)
#define SG_SLOTS 6         // graphs spanned by a 977-row window (avg graph ~15.6k rows)
#define N4_TOTAL (N_NODES / 4)          // 250,000
#define N4_PER_BLK 245                  // 1024*245 = 250,880 >= 250,000
#define FUSION_BASE 512                 // blocks 512..575 do fusion b = blk-512

// ws float offsets
#define WS_HIDPART 0                                   // 8 * 64 * 128 = 65536 floats
#define WS_TBLV (8 * B_DIM * H_DIM)                    // + NBLK*SG_SLOTS floats
#define WS_TBLG (WS_TBLV + NBLK * SG_SLOTS)            // + NBLK ints

__global__ void __launch_bounds__(256, 4)
fused_kernel(const float* __restrict__ src, const int* __restrict__ src_len,
             const float* __restrict__ W_in, const float* __restrict__ b_in,
             const float* __restrict__ node_x, const float* __restrict__ W_pred,
             const float* __restrict__ b_pred, const float* __restrict__ node_w,
             const int* __restrict__ gids,
             const float* __restrict__ pro, const float* __restrict__ W_extra,
             const float* __restrict__ b_extra, const float* __restrict__ W_hid,
             const float* __restrict__ b_hid,
             float* __restrict__ outputs, float* __restrict__ hidden_out,
             float* __restrict__ lg, float* __restrict__ hid_partial,
             float* __restrict__ tblV, int* __restrict__ tblG) {
    __shared__ float sg[SG_SLOTS];
    __shared__ float gsum[NUM_GRAPHS];
    __shared__ float sh[P_OUTF + H_DIM];
    const int tid = threadIdx.x;
    const int blk = blockIdx.x;
    if (tid < SG_SLOTS) sg[tid] = 0.0f;

    // ================= Phase A =================
    // ---- fc_in duty (blocks 0..255): outputs + per-chunk mean partials ----
    if (blk < 256) {
        int b = blk & 63;
        int chunk = blk >> 6;          // 0..3
        int h = tid & 127;
        int shalf = tid >> 7;          // 0..1, 32 s each
        float w0 = W_in[h], w1 = W_in[H_DIM + h], w2 = W_in[2 * H_DIM + h];
        float bi = b_in[h];
        int len = src_len[b];
        float facc = 0.0f;
        int s0 = chunk * 64 + shalf * 32;
        for (int s = s0; s < s0 + 32; ++s) {
            const float* sp = src + ((size_t)s * B_DIM + b) * IN_DIM;
            float v = fmaf(sp[0], w0, fmaf(sp[1], w1, fmaf(sp[2], w2, bi)));
            v = (s < len) ? v : 0.0f;
            outputs[((size_t)s * B_DIM + b) * H_DIM + h] = v;
            facc += v;
        }
        hid_partial[((size_t)(chunk * 2 + shalf) * B_DIM + b) * H_DIM + h] = facc;
    }
    __syncthreads();   // sg zeroed & visible

    // ---- lg scores + block-local masked exp-sum (all blocks) ----
    const int start = blk * RPB;
    const int bend = min(start + RPB, N_NODES);
    const int gfirst = gids[start];
    const int wid = tid >> 6;
    const int lane = tid & 63;
    const int half = lane >> 5;
    const int sub = lane & 31;
    const int wstart = start + wid * RPW;
    const int wend = min(wstart + RPW, bend);
    float4 w4 = ((const float4*)W_pred)[sub];
    float bp = b_pred[0];
    int curg = -1;
    float acc = 0.0f;
    for (int r0 = wstart; r0 < wend; r0 += 8) {
        float4 x[4];
        #pragma unroll
        for (int k = 0; k < 4; ++k) {
            int row = r0 + 2 * k + half;
            x[k] = (row < wend) ? ((const float4*)(node_x + (size_t)row * H_DIM))[sub]
                                : make_float4(0.f, 0.f, 0.f, 0.f);
        }
        float s[4];
        #pragma unroll
        for (int k = 0; k < 4; ++k)
            s[k] = x[k].x * w4.x + x[k].y * w4.y + x[k].z * w4.z + x[k].w * w4.w;
        #pragma unroll
        for (int off = 1; off < 32; off <<= 1) {
            #pragma unroll
            for (int k = 0; k < 4; ++k) s[k] += __shfl_xor(s[k], off);
        }
        if (sub == 0) {
            #pragma unroll
            for (int k = 0; k < 4; ++k) {
                int row = r0 + 2 * k + half;
                if (row < wend) {
                    float score = s[k] + bp;
                    lg[row] = score;
                    float xe = expf(score) * node_w[row];
                    int g = gids[row];
                    if (g != curg) {
                        if (curg >= 0) atomicAdd(&sg[min(curg - gfirst, SG_SLOTS - 1)], acc);
                        curg = g;
                        acc = 0.0f;
                    }
                    acc += xe;
                }
            }
        }
    }
    if (sub == 0 && curg >= 0) atomicAdd(&sg[min(curg - gfirst, SG_SLOTS - 1)], acc);
    __syncthreads();
    if (tid < SG_SLOTS) tblV[blk * SG_SLOTS + tid] = sg[tid];
    if (tid == 0) tblG[blk] = gfirst;

    // ================= grid barrier =================
    cg::this_grid().sync();

    // ================= Phase B =================
    // ---- reduce partial table (L2-hot, 24 KB) into LDS gsum ----
    if (tid < NUM_GRAPHS) gsum[tid] = 0.0f;
    __syncthreads();
    {
        int cg2 = -1;
        float a = 0.0f;
        #pragma unroll
        for (int b = tid * (NBLK / 256); b < (tid + 1) * (NBLK / 256); ++b) {  // 4 blocks/thread
            int gf = tblG[b];
            #pragma unroll
            for (int slot = 0; slot < SG_SLOTS; ++slot) {
                float v = tblV[b * SG_SLOTS + slot];
                if (v != 0.0f) {
                    int g = min(gf + slot, NUM_GRAPHS - 1);
                    if (g != cg2) {
                        if (cg2 >= 0) atomicAdd(&gsum[cg2], a);
                        cg2 = g;
                        a = 0.0f;
                    }
                    a += v;
                }
            }
        }
        if (cg2 >= 0) atomicAdd(&gsum[cg2], a);
    }
    __syncthreads();

    // ---- lg_out slice: lg -> log(clip(exp(lg)*w/(sum+eps), eps, 1)) ----
    if (tid < N4_PER_BLK) {
        int n4 = blk * N4_PER_BLK + tid;
        if (n4 < N4_TOTAL) {
            float4 l = ((const float4*)lg)[n4];
            float4 w = ((const float4*)node_w)[n4];
            int4 g = ((const int4*)gids)[n4];
            float4 r;
            r.x = logf(fminf(fmaxf(expf(l.x) * w.x / (gsum[g.x] + EPSF), EPSF), 1.0f));
            r.y = logf(fminf(fmaxf(expf(l.y) * w.y / (gsum[g.y] + EPSF), EPSF), 1.0f));
            r.z = logf(fminf(fmaxf(expf(l.z) * w.z / (gsum[g.z] + EPSF), EPSF), 1.0f));
            r.w = logf(fminf(fmaxf(expf(l.w) * w.w / (gsum[g.w] + EPSF), EPSF), 1.0f));
            ((float4*)lg)[n4] = r;
        }
    }

    // ---- fusion duty (blocks FUSION_BASE..FUSION_BASE+63) ----
    if (blk >= FUSION_BASE && blk < FUSION_BASE + B_DIM) {
        int b = blk - FUSION_BASE;
        if (tid < P_OUTF) {
            float a = b_extra[tid];
            #pragma unroll
            for (int k = 0; k < P_INF; ++k) a += pro[b * P_INF + k] * W_extra[k * P_OUTF + tid];
            sh[tid] = tanhf(a);
        }
        if (tid < H_DIM) {
            float m = 0.0f;
            #pragma unroll
            for (int c = 0; c < 8; ++c) m += hid_partial[((size_t)c * B_DIM + b) * H_DIM + tid];
            sh[P_OUTF + tid] = m * (1.0f / S_DIM);
        }
        __syncthreads();
        if (tid < H_DIM) {
            float a = b_hid[tid];
            #pragma unroll 8
            for (int k = 0; k < P_OUTF + H_DIM; ++k) a += sh[k] * W_hid[k * H_DIM + tid];
            hidden_out[(size_t)b * H_DIM + tid] = tanhf(a);
        }
    }
}

extern "C" void kernel_launch(void* const* d_in, const int* in_sizes, int n_in,
                              void* d_out, int out_size, void* d_ws, size_t ws_size,
                              hipStream_t stream) {
    const float* src      = (const float*)d_in[0];
    const int*   src_len  = (const int*)d_in[1];
    const float* node_x   = (const float*)d_in[2];
    const float* node_w   = (const float*)d_in[3];
    const int*   gids     = (const int*)d_in[4];
    const float* pro      = (const float*)d_in[5];
    const float* W_in     = (const float*)d_in[6];
    const float* b_in     = (const float*)d_in[7];
    const float* W_pred   = (const float*)d_in[8];
    const float* b_pred   = (const float*)d_in[9];
    const float* W_extra  = (const float*)d_in[10];
    const float* b_extra  = (const float*)d_in[11];
    const float* W_hid    = (const float*)d_in[12];
    const float* b_hid    = (const float*)d_in[13];

    float* out = (float*)d_out;
    float* outputs = out + OUT_OUTPUTS;
    float* hidden  = out + OUT_HIDDEN;
    float* lg      = out + OUT_LG;     // scratch for scores, overwritten in-place

    float* ws = (float*)d_ws;
    float* hid_partial = ws + WS_HIDPART;
    float* tblV = ws + WS_TBLV;
    int*   tblG = (int*)(ws + WS_TBLG);

    void* args[] = {
        (void*)&src, (void*)&src_len, (void*)&W_in, (void*)&b_in,
        (void*)&node_x, (void*)&W_pred, (void*)&b_pred, (void*)&node_w,
        (void*)&gids, (void*)&pro, (void*)&W_extra, (void*)&b_extra,
        (void*)&W_hid, (void*)&b_hid,
        (void*)&outputs, (void*)&hidden, (void*)&lg, (void*)&hid_partial,
        (void*)&tblV, (void*)&tblG
    };
    hipLaunchCooperativeKernel((const void*)fused_kernel, dim3(NBLK), dim3(256),
                               args, 0, stream);
}

// Round 6
// 143.023 us; speedup vs baseline: 2.0418x; 2.0418x over previous
//
#include <hip/hip_runtime.h>

#define S_DIM 256
#define B_DIM 64
#define IN_DIM 3
#define H_DIM 128
#define N_NODES 1000000
#define NM1 (N_NODES - 1)
#define P_INF 8
#define P_OUTF 32
#define NUM_GRAPHS 64
#define EPSF 1e-6f

// d_out float offsets
#define OUT_OUTPUTS 0
#define OUT_HIDDEN (S_DIM * B_DIM * H_DIM)            // 2097152
#define OUT_LG (OUT_HIDDEN + B_DIM * H_DIM)           // 2105344

// main kernel geometry
#define NBLK 2048
#define RPB 489            // ceil(1e6 / 2048)
#define RPW 123            // rows per wave (4 waves: 492 >= 489)
#define SG_SLOTS 6

// ws float offsets
#define WS_HIDPART 0                                   // 8 * 64 * 128 floats
#define WS_TBLV (8 * B_DIM * H_DIM)                    // + NBLK*SG_SLOTS floats
#define WS_TBLG (WS_TBLV + NBLK * SG_SLOTS)            // + NBLK ints

// ---------------------------------------------------------------------------
// K1 "main": lg scores + block-local masked exp-sums into a no-init partial
// table. Blocks 0..255 also do fc_in. Inner loop: lane = 8*row + piece.
// All loads branchless & issued up front; segment accumulation is pure
// register ops per lane (rows == lane mod 8); no loads on the reduce chain.
// No max subtraction: lg is O(3); eps-shift error ~1e-9 << threshold.
// ---------------------------------------------------------------------------
__global__ void __launch_bounds__(256)
main_kernel(const float* __restrict__ src, const int* __restrict__ src_len,
            const float* __restrict__ W_in, const float* __restrict__ b_in,
            const float* __restrict__ node_x, const float* __restrict__ W_pred,
            const float* __restrict__ b_pred, const float* __restrict__ node_w,
            const int* __restrict__ gids,
            float* __restrict__ outputs, float* __restrict__ hid_partial,
            float* __restrict__ lg, float* __restrict__ tblV, int* __restrict__ tblG) {
    __shared__ float sg[SG_SLOTS];
    const int tid = threadIdx.x;
    const int blk = blockIdx.x;
    if (tid < SG_SLOTS) sg[tid] = 0.0f;

    // ---- fc_in duty (blocks 0..255) ----
    if (blk < 256) {
        int b = blk & 63;
        int chunk = blk >> 6;
        int h = tid & 127;
        int shalf = tid >> 7;
        float w0 = W_in[h], w1 = W_in[H_DIM + h], w2 = W_in[2 * H_DIM + h];
        float bi = b_in[h];
        int len = src_len[b];
        float facc = 0.0f;
        int s0 = chunk * 64 + shalf * 32;
        for (int s = s0; s < s0 + 32; ++s) {
            const float* sp = src + ((size_t)s * B_DIM + b) * IN_DIM;
            float v = fmaf(sp[0], w0, fmaf(sp[1], w1, fmaf(sp[2], w2, bi)));
            v = (s < len) ? v : 0.0f;
            outputs[((size_t)s * B_DIM + b) * H_DIM + h] = v;
            facc += v;
        }
        hid_partial[((size_t)(chunk * 2 + shalf) * B_DIM + b) * H_DIM + h] = facc;
    }
    __syncthreads();   // sg zeroed & visible

    // ---- lg + exp-sum duty ----
    const int start = blk * RPB;
    const int bend = min(start + RPB, N_NODES);
    const int gfirst = (start < N_NODES) ? gids[start] : 0;
    const int wid = tid >> 6;
    const int lane = tid & 63;
    const int p = lane & 7;        // piece within row (32 floats, 4 x float4)
    const int rloc = lane >> 3;    // row within the 8-row group
    const int wstart = start + wid * RPW;
    const int wend = min(wstart + RPW, bend);

    float4 wch0 = ((const float4*)W_pred)[p];
    float4 wch1 = ((const float4*)W_pred)[p + 8];
    float4 wch2 = ((const float4*)W_pred)[p + 16];
    float4 wch3 = ((const float4*)W_pred)[p + 24];
    const float bp = b_pred[0];

    int curg = -1;
    float acc = 0.0f;

    for (int r0 = wstart; r0 < wend; r0 += 8) {
        // side data for rows r0..r0+7 (8-way duplicated; 1-2 cachelines)
        int sidx = min(r0 + p, NM1);
        float wv = node_w[sidx];
        int gv = gids[sidx];
        // main row data: 8 rows x 512B = 4KB per wave, branchless
        int xrow = min(r0 + rloc, NM1);
        const float4* xb = (const float4*)(node_x + (size_t)xrow * H_DIM);
        float4 x0 = xb[p];
        float4 x1 = xb[p + 8];
        float4 x2 = xb[p + 16];
        float4 x3 = xb[p + 24];
        float s = x0.x * wch0.x + x0.y * wch0.y + x0.z * wch0.z + x0.w * wch0.w;
        s += x1.x * wch1.x + x1.y * wch1.y + x1.z * wch1.z + x1.w * wch1.w;
        s += x2.x * wch2.x + x2.y * wch2.y + x2.z * wch2.z + x2.w * wch2.w;
        s += x3.x * wch3.x + x3.y * wch3.y + x3.z * wch3.z + x3.w * wch3.w;
        // reduce across the 8 pieces of each row
        s += __shfl_xor(s, 1);
        s += __shfl_xor(s, 2);
        s += __shfl_xor(s, 4);
        // lane j grabs row j's sum (from lane 8j)
        float rowsum = __shfl(s, (lane & 7) * 8);
        int myrow = r0 + p;
        if (lane < 8 && myrow < wend) {
            float score = rowsum + bp;
            lg[myrow] = score;                  // 8 consecutive floats, coalesced
            float xe = expf(score) * wv;
            if (gv != curg) {
                if (curg >= 0) atomicAdd(&sg[min(curg - gfirst, SG_SLOTS - 1)], acc);
                curg = gv;
                acc = 0.0f;
            }
            acc += xe;
        }
    }
    if (curg >= 0) atomicAdd(&sg[min(curg - gfirst, SG_SLOTS - 1)], acc);
    __syncthreads();
    if (tid < SG_SLOTS) tblV[blk * SG_SLOTS + tid] = sg[tid];
    if (tid == 0) tblG[blk] = gfirst;
}

// ---------------------------------------------------------------------------
// K2 "finish": blocks 0..976 reduce the partial table into LDS gsum[64] then
// transform lg in-place (float4). Blocks 977..1040 do fusion.
// ---------------------------------------------------------------------------
#define LGOUT_BLOCKS 977

__global__ void __launch_bounds__(256)
finish_kernel(const float* __restrict__ tblV, const int* __restrict__ tblG,
              float* __restrict__ lg, const int* __restrict__ gids,
              const float* __restrict__ node_w,
              const float* __restrict__ pro, const float* __restrict__ W_extra,
              const float* __restrict__ b_extra, const float* __restrict__ W_hid,
              const float* __restrict__ b_hid, const float* __restrict__ hid_partial,
              float* __restrict__ hidden_out) {
    const int tid = threadIdx.x;
    const int blk = blockIdx.x;

    if (blk >= LGOUT_BLOCKS) {
        int b = blk - LGOUT_BLOCKS;
        __shared__ float sh[P_OUTF + H_DIM];
        if (tid < P_OUTF) {
            float a = b_extra[tid];
            #pragma unroll
            for (int k = 0; k < P_INF; ++k) a += pro[b * P_INF + k] * W_extra[k * P_OUTF + tid];
            sh[tid] = tanhf(a);
        }
        if (tid < H_DIM) {
            float m = 0.0f;
            #pragma unroll
            for (int c = 0; c < 8; ++c) m += hid_partial[((size_t)c * B_DIM + b) * H_DIM + tid];
            sh[P_OUTF + tid] = m * (1.0f / S_DIM);
        }
        __syncthreads();
        if (tid < H_DIM) {
            float a = b_hid[tid];
            #pragma unroll 8
            for (int k = 0; k < P_OUTF + H_DIM; ++k) a += sh[k] * W_hid[k * H_DIM + tid];
            hidden_out[(size_t)b * H_DIM + tid] = tanhf(a);
        }
        return;
    }

    __shared__ float gsum[NUM_GRAPHS];
    if (tid < NUM_GRAPHS) gsum[tid] = 0.0f;
    __syncthreads();
    {
        int cg2 = -1;
        float a = 0.0f;
        for (int b = tid * (NBLK / 256); b < (tid + 1) * (NBLK / 256); ++b) {  // 8 blocks/thread
            int gf = tblG[b];
            #pragma unroll
            for (int slot = 0; slot < SG_SLOTS; ++slot) {
                float v = tblV[b * SG_SLOTS + slot];
                if (v != 0.0f) {
                    int g = min(gf + slot, NUM_GRAPHS - 1);
                    if (g != cg2) {
                        if (cg2 >= 0) atomicAdd(&gsum[cg2], a);
                        cg2 = g;
                        a = 0.0f;
                    }
                    a += v;
                }
            }
        }
        if (cg2 >= 0) atomicAdd(&gsum[cg2], a);
    }
    __syncthreads();

    int n4 = blk * 256 + tid;
    if (n4 >= N_NODES / 4) return;
    float4 l = ((const float4*)lg)[n4];
    float4 w = ((const float4*)node_w)[n4];
    int4 g = ((const int4*)gids)[n4];
    float4 r;
    r.x = logf(fminf(fmaxf(expf(l.x) * w.x / (gsum[g.x] + EPSF), EPSF), 1.0f));
    r.y = logf(fminf(fmaxf(expf(l.y) * w.y / (gsum[g.y] + EPSF), EPSF), 1.0f));
    r.z = logf(fminf(fmaxf(expf(l.z) * w.z / (gsum[g.z] + EPSF), EPSF), 1.0f));
    r.w = logf(fminf(fmaxf(expf(l.w) * w.w / (gsum[g.w] + EPSF), EPSF), 1.0f));
    ((float4*)lg)[n4] = r;
}

extern "C" void kernel_launch(void* const* d_in, const int* in_sizes, int n_in,
                              void* d_out, int out_size, void* d_ws, size_t ws_size,
                              hipStream_t stream) {
    const float* src      = (const float*)d_in[0];
    const int*   src_len  = (const int*)d_in[1];
    const float* node_x   = (const float*)d_in[2];
    const float* node_w   = (const float*)d_in[3];
    const int*   gids     = (const int*)d_in[4];
    const float* pro      = (const float*)d_in[5];
    const float* W_in     = (const float*)d_in[6];
    const float* b_in     = (const float*)d_in[7];
    const float* W_pred   = (const float*)d_in[8];
    const float* b_pred   = (const float*)d_in[9];
    const float* W_extra  = (const float*)d_in[10];
    const float* b_extra  = (const float*)d_in[11];
    const float* W_hid    = (const float*)d_in[12];
    const float* b_hid    = (const float*)d_in[13];

    float* out = (float*)d_out;
    float* outputs = out + OUT_OUTPUTS;
    float* hidden  = out + OUT_HIDDEN;
    float* lg      = out + OUT_LG;     // scratch for scores, overwritten in-place

    float* ws = (float*)d_ws;
    float* hid_partial = ws + WS_HIDPART;
    float* tblV = ws + WS_TBLV;
    int*   tblG = (int*)(ws + WS_TBLG);

    main_kernel<<<NBLK, 256, 0, stream>>>(src, src_len, W_in, b_in,
                                          node_x, W_pred, b_pred, node_w, gids,
                                          outputs, hid_partial, lg, tblV, tblG);

    finish_kernel<<<LGOUT_BLOCKS + B_DIM, 256, 0, stream>>>(tblV, tblG, lg, gids, node_w,
                                                            pro, W_extra, b_extra, W_hid,
                                                            b_hid, hid_partial, hidden);
}

// Round 7
// 140.381 us; speedup vs baseline: 2.0802x; 1.0188x over previous
//
#include <hip/hip_runtime.h>

#define S_DIM 256
#define B_DIM 64
#define IN_DIM 3
#define H_DIM 128
#define N_NODES 1000000
#define NM1 (N_NODES - 1)
#define P_INF 8
#define P_OUTF 32
#define NUM_GRAPHS 64
#define EPSF 1e-6f

// d_out float offsets
#define OUT_OUTPUTS 0
#define OUT_HIDDEN (S_DIM * B_DIM * H_DIM)            // 2097152
#define OUT_LG (OUT_HIDDEN + B_DIM * H_DIM)           // 2105344

// main kernel geometry
#define NBLK 2048
#define RPB 489            // ceil(1e6 / 2048)
#define RPW 123            // rows per wave (4 waves: 492 >= 489)
#define SG_SLOTS 6

// ws float offsets
#define WS_HIDPART 0                                   // 8 * 64 * 128 floats
#define WS_TBLV (8 * B_DIM * H_DIM)                    // + NBLK*SG_SLOTS floats
#define WS_TBLG (WS_TBLV + NBLK * SG_SLOTS)            // + NBLK ints

// ---------------------------------------------------------------------------
// K1 "main": lg scores + block-local masked exp-sums. Blocks 0..255 also do
// fc_in. Inner loop: lane = 8*rloc + p; 8 rows (4 KB) per iteration with an
// explicit 2-deep software pipeline: iteration i+1's loads are issued before
// iteration i's reduce/tail, so each wave keeps ~8 KB in flight.
// No max subtraction: lg is O(3); eps-shift error ~1e-9 << threshold.
// ---------------------------------------------------------------------------
__global__ void __launch_bounds__(256)
main_kernel(const float* __restrict__ src, const int* __restrict__ src_len,
            const float* __restrict__ W_in, const float* __restrict__ b_in,
            const float* __restrict__ node_x, const float* __restrict__ W_pred,
            const float* __restrict__ b_pred, const float* __restrict__ node_w,
            const int* __restrict__ gids,
            float* __restrict__ outputs, float* __restrict__ hid_partial,
            float* __restrict__ lg, float* __restrict__ tblV, int* __restrict__ tblG) {
    __shared__ float sg[SG_SLOTS];
    const int tid = threadIdx.x;
    const int blk = blockIdx.x;
    if (tid < SG_SLOTS) sg[tid] = 0.0f;

    // ---- fc_in duty (blocks 0..255) ----
    if (blk < 256) {
        int b = blk & 63;
        int chunk = blk >> 6;
        int h = tid & 127;
        int shalf = tid >> 7;
        float w0 = W_in[h], w1 = W_in[H_DIM + h], w2 = W_in[2 * H_DIM + h];
        float bi = b_in[h];
        int len = src_len[b];
        float facc = 0.0f;
        int s0 = chunk * 64 + shalf * 32;
        for (int s = s0; s < s0 + 32; ++s) {
            const float* sp = src + ((size_t)s * B_DIM + b) * IN_DIM;
            float v = fmaf(sp[0], w0, fmaf(sp[1], w1, fmaf(sp[2], w2, bi)));
            v = (s < len) ? v : 0.0f;
            outputs[((size_t)s * B_DIM + b) * H_DIM + h] = v;
            facc += v;
        }
        hid_partial[((size_t)(chunk * 2 + shalf) * B_DIM + b) * H_DIM + h] = facc;
    }
    __syncthreads();   // sg zeroed & visible

    // ---- lg + exp-sum duty ----
    const int start = blk * RPB;
    const int bend = min(start + RPB, N_NODES);
    const int gfirst = gids[min(start, NM1)];
    const int wid = tid >> 6;
    const int lane = tid & 63;
    const int p = lane & 7;        // piece within row (16 floats? no: 4 x float4 strided)
    const int rloc = lane >> 3;    // row within the 8-row group
    const int wstart = start + wid * RPW;
    const int wend = min(wstart + RPW, bend);

    float4 wch0 = ((const float4*)W_pred)[p];
    float4 wch1 = ((const float4*)W_pred)[p + 8];
    float4 wch2 = ((const float4*)W_pred)[p + 16];
    float4 wch3 = ((const float4*)W_pred)[p + 24];
    const float bp = b_pred[0];

    int curg = -1;
    float acc = 0.0f;

    float4 cx0, cx1, cx2, cx3;
    float cwv = 0.0f;
    int cgv = 0;

#define LOADG(R0, X0, X1, X2, X3, WV, GV)                                   \
    {                                                                        \
        int sidx = min((R0) + p, NM1);                                       \
        WV = node_w[sidx];                                                   \
        GV = gids[sidx];                                                     \
        int xrow = min((R0) + rloc, NM1);                                    \
        const float4* xb = (const float4*)(node_x + (size_t)xrow * H_DIM);   \
        X0 = xb[p];                                                          \
        X1 = xb[p + 8];                                                      \
        X2 = xb[p + 16];                                                     \
        X3 = xb[p + 24];                                                     \
    }

    if (wstart < wend) {
        LOADG(wstart, cx0, cx1, cx2, cx3, cwv, cgv);
    }

    for (int r0 = wstart; r0 < wend; r0 += 8) {
        float4 nx0, nx1, nx2, nx3;
        float nwv = 0.0f;
        int ngv = 0;
        const int nr0 = r0 + 8;
        if (nr0 < wend) {                 // wave-uniform branch
            LOADG(nr0, nx0, nx1, nx2, nx3, nwv, ngv);
        }
        // compute on current regs while next loads are in flight
        float s = cx0.x * wch0.x + cx0.y * wch0.y + cx0.z * wch0.z + cx0.w * wch0.w;
        s += cx1.x * wch1.x + cx1.y * wch1.y + cx1.z * wch1.z + cx1.w * wch1.w;
        s += cx2.x * wch2.x + cx2.y * wch2.y + cx2.z * wch2.z + cx2.w * wch2.w;
        s += cx3.x * wch3.x + cx3.y * wch3.y + cx3.z * wch3.z + cx3.w * wch3.w;
        s += __shfl_xor(s, 1);
        s += __shfl_xor(s, 2);
        s += __shfl_xor(s, 4);
        float rowsum = __shfl(s, p * 8);   // lane j gets row j's sum
        int myrow = r0 + p;
        if (lane < 8 && myrow < wend) {
            float score = rowsum + bp;
            lg[myrow] = score;             // 8 consecutive floats, coalesced
            float xe = __expf(score) * cwv;
            if (cgv != curg) {
                if (curg >= 0) atomicAdd(&sg[min(curg - gfirst, SG_SLOTS - 1)], acc);
                curg = cgv;
                acc = 0.0f;
            }
            acc += xe;
        }
        cx0 = nx0; cx1 = nx1; cx2 = nx2; cx3 = nx3;
        cwv = nwv; cgv = ngv;
    }
#undef LOADG
    if (curg >= 0) atomicAdd(&sg[min(curg - gfirst, SG_SLOTS - 1)], acc);
    __syncthreads();
    if (tid < SG_SLOTS) tblV[blk * SG_SLOTS + tid] = sg[tid];
    if (tid == 0) tblG[blk] = gfirst;
}

// ---------------------------------------------------------------------------
// K2 "finish": blocks 0..976 reduce the partial table into LDS gsum[64] then
// transform lg in-place (float4). Blocks 977..1040 do fusion.
// ---------------------------------------------------------------------------
#define LGOUT_BLOCKS 977

__global__ void __launch_bounds__(256)
finish_kernel(const float* __restrict__ tblV, const int* __restrict__ tblG,
              float* __restrict__ lg, const int* __restrict__ gids,
              const float* __restrict__ node_w,
              const float* __restrict__ pro, const float* __restrict__ W_extra,
              const float* __restrict__ b_extra, const float* __restrict__ W_hid,
              const float* __restrict__ b_hid, const float* __restrict__ hid_partial,
              float* __restrict__ hidden_out) {
    const int tid = threadIdx.x;
    const int blk = blockIdx.x;

    if (blk >= LGOUT_BLOCKS) {
        int b = blk - LGOUT_BLOCKS;
        __shared__ float sh[P_OUTF + H_DIM];
        if (tid < P_OUTF) {
            float a = b_extra[tid];
            #pragma unroll
            for (int k = 0; k < P_INF; ++k) a += pro[b * P_INF + k] * W_extra[k * P_OUTF + tid];
            sh[tid] = tanhf(a);
        }
        if (tid < H_DIM) {
            float m = 0.0f;
            #pragma unroll
            for (int c = 0; c < 8; ++c) m += hid_partial[((size_t)c * B_DIM + b) * H_DIM + tid];
            sh[P_OUTF + tid] = m * (1.0f / S_DIM);
        }
        __syncthreads();
        if (tid < H_DIM) {
            float a = b_hid[tid];
            #pragma unroll 8
            for (int k = 0; k < P_OUTF + H_DIM; ++k) a += sh[k] * W_hid[k * H_DIM + tid];
            hidden_out[(size_t)b * H_DIM + tid] = tanhf(a);
        }
        return;
    }

    __shared__ float gsum[NUM_GRAPHS];
    if (tid < NUM_GRAPHS) gsum[tid] = 0.0f;
    __syncthreads();
    {
        int cg2 = -1;
        float a = 0.0f;
        for (int b = tid * (NBLK / 256); b < (tid + 1) * (NBLK / 256); ++b) {  // 8 blocks/thread
            int gf = tblG[b];
            #pragma unroll
            for (int slot = 0; slot < SG_SLOTS; ++slot) {
                float v = tblV[b * SG_SLOTS + slot];
                if (v != 0.0f) {
                    int g = min(gf + slot, NUM_GRAPHS - 1);
                    if (g != cg2) {
                        if (cg2 >= 0) atomicAdd(&gsum[cg2], a);
                        cg2 = g;
                        a = 0.0f;
                    }
                    a += v;
                }
            }
        }
        if (cg2 >= 0) atomicAdd(&gsum[cg2], a);
    }
    __syncthreads();

    int n4 = blk * 256 + tid;
    if (n4 >= N_NODES / 4) return;
    float4 l = ((const float4*)lg)[n4];
    float4 w = ((const float4*)node_w)[n4];
    int4 g = ((const int4*)gids)[n4];
    float4 r;
    r.x = __logf(fminf(fmaxf(__expf(l.x) * w.x / (gsum[g.x] + EPSF), EPSF), 1.0f));
    r.y = __logf(fminf(fmaxf(__expf(l.y) * w.y / (gsum[g.y] + EPSF), EPSF), 1.0f));
    r.z = __logf(fminf(fmaxf(__expf(l.z) * w.z / (gsum[g.z] + EPSF), EPSF), 1.0f));
    r.w = __logf(fminf(fmaxf(__expf(l.w) * w.w / (gsum[g.w] + EPSF), EPSF), 1.0f));
    ((float4*)lg)[n4] = r;
}

extern "C" void kernel_launch(void* const* d_in, const int* in_sizes, int n_in,
                              void* d_out, int out_size, void* d_ws, size_t ws_size,
                              hipStream_t stream) {
    const float* src      = (const float*)d_in[0];
    const int*   src_len  = (const int*)d_in[1];
    const float* node_x   = (const float*)d_in[2];
    const float* node_w   = (const float*)d_in[3];
    const int*   gids     = (const int*)d_in[4];
    const float* pro      = (const float*)d_in[5];
    const float* W_in     = (const float*)d_in[6];
    const float* b_in     = (const float*)d_in[7];
    const float* W_pred   = (const float*)d_in[8];
    const float* b_pred   = (const float*)d_in[9];
    const float* W_extra  = (const float*)d_in[10];
    const float* b_extra  = (const float*)d_in[11];
    const float* W_hid    = (const float*)d_in[12];
    const float* b_hid    = (const float*)d_in[13];

    float* out = (float*)d_out;
    float* outputs = out + OUT_OUTPUTS;
    float* hidden  = out + OUT_HIDDEN;
    float* lg      = out + OUT_LG;     // scratch for scores, overwritten in-place

    float* ws = (float*)d_ws;
    float* hid_partial = ws + WS_HIDPART;
    float* tblV = ws + WS_TBLV;
    int*   tblG = (int*)(ws + WS_TBLG);

    main_kernel<<<NBLK, 256, 0, stream>>>(src, src_len, W_in, b_in,
                                          node_x, W_pred, b_pred, node_w, gids,
                                          outputs, hid_partial, lg, tblV, tblG);

    finish_kernel<<<LGOUT_BLOCKS + B_DIM, 256, 0, stream>>>(tblV, tblG, lg, gids, node_w,
                                                            pro, W_extra, b_extra, W_hid,
                                                            b_hid, hid_partial, hidden);
}

// Round 8
// 121.971 us; speedup vs baseline: 2.3942x; 1.1509x over previous
//
#include <hip/hip_runtime.h>

#define S_DIM 256
#define B_DIM 64
#define IN_DIM 3
#define H_DIM 128
#define N_NODES 1000000
#define NM1 (N_NODES - 1)
#define P_INF 8
#define P_OUTF 32
#define NUM_GRAPHS 64
#define EPSF 1e-6f

// d_out float offsets
#define OUT_OUTPUTS 0
#define OUT_HIDDEN (S_DIM * B_DIM * H_DIM)            // 2097152
#define OUT_LG (OUT_HIDDEN + B_DIM * H_DIM)           // 2105344

// main kernel geometry: 1024 blocks x 512 threads (8 waves). Each block owns
// a contiguous 977-row range; its 8 waves interleave 8-row groups round-robin
// so the block's read front advances 32 KB per round -> 1024 long streams
// instead of 8192 short ones.
#define NBLK 1024
#define TPB 512
#define RPB 977            // 1024*977 = 1,000,448 >= 1e6
#define GSTEP 64           // 8 waves x 8 rows
#define SG_SLOTS 6

// ws float offsets
#define WS_HIDPART 0                                   // 16 * 64 * 128 floats
#define WS_TBLV (16 * B_DIM * H_DIM)                   // + NBLK*SG_SLOTS floats
#define WS_TBLG (WS_TBLV + NBLK * SG_SLOTS)            // + NBLK ints

// ---------------------------------------------------------------------------
// K1 "main": lg scores + block-local masked exp-sums into a no-init partial
// table. Blocks 0..255 also do fc_in. 2-deep pipeline per wave kept.
// No max subtraction: lg is O(3); eps-shift error ~1e-9 << threshold.
// ---------------------------------------------------------------------------
__global__ void __launch_bounds__(TPB)
main_kernel(const float* __restrict__ src, const int* __restrict__ src_len,
            const float* __restrict__ W_in, const float* __restrict__ b_in,
            const float* __restrict__ node_x, const float* __restrict__ W_pred,
            const float* __restrict__ b_pred, const float* __restrict__ node_w,
            const int* __restrict__ gids,
            float* __restrict__ outputs, float* __restrict__ hid_partial,
            float* __restrict__ lg, float* __restrict__ tblV, int* __restrict__ tblG) {
    __shared__ float sg[SG_SLOTS];
    const int tid = threadIdx.x;
    const int blk = blockIdx.x;
    if (tid < SG_SLOTS) sg[tid] = 0.0f;

    // ---- fc_in duty (blocks 0..255, all 512 threads) ----
    if (blk < 256) {
        int b = blk & 63;
        int chunk = blk >> 6;          // 0..3 (64 s each)
        int h = tid & 127;
        int sq = tid >> 7;             // 0..3 (16 s each)
        float w0 = W_in[h], w1 = W_in[H_DIM + h], w2 = W_in[2 * H_DIM + h];
        float bi = b_in[h];
        int len = src_len[b];
        float facc = 0.0f;
        int s0 = chunk * 64 + sq * 16;
        for (int s = s0; s < s0 + 16; ++s) {
            const float* sp = src + ((size_t)s * B_DIM + b) * IN_DIM;
            float v = fmaf(sp[0], w0, fmaf(sp[1], w1, fmaf(sp[2], w2, bi)));
            v = (s < len) ? v : 0.0f;
            outputs[((size_t)s * B_DIM + b) * H_DIM + h] = v;
            facc += v;
        }
        hid_partial[((size_t)(chunk * 4 + sq) * B_DIM + b) * H_DIM + h] = facc;
    }
    __syncthreads();   // sg zeroed & visible

    // ---- lg + exp-sum duty ----
    const int start = blk * RPB;
    const int bend = min(start + RPB, N_NODES);
    const int gfirst = gids[min(start, NM1)];
    const int w = tid >> 6;        // wave 0..7
    const int lane = tid & 63;
    const int p = lane & 7;        // piece within row
    const int rloc = lane >> 3;    // row within the 8-row group

    float4 wch0 = ((const float4*)W_pred)[p];
    float4 wch1 = ((const float4*)W_pred)[p + 8];
    float4 wch2 = ((const float4*)W_pred)[p + 16];
    float4 wch3 = ((const float4*)W_pred)[p + 24];
    const float bp = b_pred[0];

    int curg = -1;
    float acc = 0.0f;

    float4 cx0, cx1, cx2, cx3;
    float cwv = 0.0f;
    int cgv = 0;

#define LOADG(R0, X0, X1, X2, X3, WV, GV)                                   \
    {                                                                        \
        int sidx = min((R0) + p, NM1);                                       \
        WV = node_w[sidx];                                                   \
        GV = gids[sidx];                                                     \
        int xrow = min((R0) + rloc, NM1);                                    \
        const float4* xb = (const float4*)(node_x + (size_t)xrow * H_DIM);   \
        X0 = xb[p];                                                          \
        X1 = xb[p + 8];                                                      \
        X2 = xb[p + 16];                                                     \
        X3 = xb[p + 24];                                                     \
    }

    int r0 = start + w * 8;
    if (r0 < bend) {
        LOADG(r0, cx0, cx1, cx2, cx3, cwv, cgv);
    }
    while (r0 < bend) {
        const int nr0 = r0 + GSTEP;
        float4 nx0, nx1, nx2, nx3;
        float nwv = 0.0f;
        int ngv = 0;
        if (nr0 < bend) {              // wave-uniform branch
            LOADG(nr0, nx0, nx1, nx2, nx3, nwv, ngv);
        }
        // compute current group while next loads are in flight
        float s = cx0.x * wch0.x + cx0.y * wch0.y + cx0.z * wch0.z + cx0.w * wch0.w;
        s += cx1.x * wch1.x + cx1.y * wch1.y + cx1.z * wch1.z + cx1.w * wch1.w;
        s += cx2.x * wch2.x + cx2.y * wch2.y + cx2.z * wch2.z + cx2.w * wch2.w;
        s += cx3.x * wch3.x + cx3.y * wch3.y + cx3.z * wch3.z + cx3.w * wch3.w;
        s += __shfl_xor(s, 1);
        s += __shfl_xor(s, 2);
        s += __shfl_xor(s, 4);
        float rowsum = __shfl(s, p * 8);   // lane j gets row j's sum
        int myrow = r0 + p;
        if (lane < 8 && myrow < bend) {
            float score = rowsum + bp;
            lg[myrow] = score;             // 8 consecutive floats, coalesced
            float xe = __expf(score) * cwv;
            if (cgv != curg) {
                if (curg >= 0) atomicAdd(&sg[min(curg - gfirst, SG_SLOTS - 1)], acc);
                curg = cgv;
                acc = 0.0f;
            }
            acc += xe;
        }
        cx0 = nx0; cx1 = nx1; cx2 = nx2; cx3 = nx3;
        cwv = nwv; cgv = ngv;
        r0 = nr0;
    }
#undef LOADG
    if (curg >= 0) atomicAdd(&sg[min(curg - gfirst, SG_SLOTS - 1)], acc);
    __syncthreads();
    if (tid < SG_SLOTS) tblV[blk * SG_SLOTS + tid] = sg[tid];
    if (tid == 0) tblG[blk] = gfirst;
}

// ---------------------------------------------------------------------------
// K2 "finish": blocks 0..976 reduce the partial table into LDS gsum[64] then
// transform lg in-place (float4). Blocks 977..1040 do fusion.
// ---------------------------------------------------------------------------
#define LGOUT_BLOCKS 977

__global__ void __launch_bounds__(256)
finish_kernel(const float* __restrict__ tblV, const int* __restrict__ tblG,
              float* __restrict__ lg, const int* __restrict__ gids,
              const float* __restrict__ node_w,
              const float* __restrict__ pro, const float* __restrict__ W_extra,
              const float* __restrict__ b_extra, const float* __restrict__ W_hid,
              const float* __restrict__ b_hid, const float* __restrict__ hid_partial,
              float* __restrict__ hidden_out) {
    const int tid = threadIdx.x;
    const int blk = blockIdx.x;

    if (blk >= LGOUT_BLOCKS) {
        int b = blk - LGOUT_BLOCKS;
        __shared__ float sh[P_OUTF + H_DIM];
        if (tid < P_OUTF) {
            float a = b_extra[tid];
            #pragma unroll
            for (int k = 0; k < P_INF; ++k) a += pro[b * P_INF + k] * W_extra[k * P_OUTF + tid];
            sh[tid] = tanhf(a);
        }
        if (tid < H_DIM) {
            float m = 0.0f;
            #pragma unroll
            for (int c = 0; c < 16; ++c) m += hid_partial[((size_t)c * B_DIM + b) * H_DIM + tid];
            sh[P_OUTF + tid] = m * (1.0f / S_DIM);
        }
        __syncthreads();
        if (tid < H_DIM) {
            float a = b_hid[tid];
            #pragma unroll 8
            for (int k = 0; k < P_OUTF + H_DIM; ++k) a += sh[k] * W_hid[k * H_DIM + tid];
            hidden_out[(size_t)b * H_DIM + tid] = tanhf(a);
        }
        return;
    }

    __shared__ float gsum[NUM_GRAPHS];
    if (tid < NUM_GRAPHS) gsum[tid] = 0.0f;
    __syncthreads();
    {
        int cg2 = -1;
        float a = 0.0f;
        for (int b = tid * (NBLK / 256); b < (tid + 1) * (NBLK / 256); ++b) {  // 4 blocks/thread
            int gf = tblG[b];
            #pragma unroll
            for (int slot = 0; slot < SG_SLOTS; ++slot) {
                float v = tblV[b * SG_SLOTS + slot];
                if (v != 0.0f) {
                    int g = min(gf + slot, NUM_GRAPHS - 1);
                    if (g != cg2) {
                        if (cg2 >= 0) atomicAdd(&gsum[cg2], a);
                        cg2 = g;
                        a = 0.0f;
                    }
                    a += v;
                }
            }
        }
        if (cg2 >= 0) atomicAdd(&gsum[cg2], a);
    }
    __syncthreads();

    int n4 = blk * 256 + tid;
    if (n4 >= N_NODES / 4) return;
    float4 l = ((const float4*)lg)[n4];
    float4 w = ((const float4*)node_w)[n4];
    int4 g = ((const int4*)gids)[n4];
    float4 r;
    r.x = __logf(fminf(fmaxf(__expf(l.x) * w.x / (gsum[g.x] + EPSF), EPSF), 1.0f));
    r.y = __logf(fminf(fmaxf(__expf(l.y) * w.y / (gsum[g.y] + EPSF), EPSF), 1.0f));
    r.z = __logf(fminf(fmaxf(__expf(l.z) * w.z / (gsum[g.z] + EPSF), EPSF), 1.0f));
    r.w = __logf(fminf(fmaxf(__expf(l.w) * w.w / (gsum[g.w] + EPSF), EPSF), 1.0f));
    ((float4*)lg)[n4] = r;
}

extern "C" void kernel_launch(void* const* d_in, const int* in_sizes, int n_in,
                              void* d_out, int out_size, void* d_ws, size_t ws_size,
                              hipStream_t stream) {
    const float* src      = (const float*)d_in[0];
    const int*   src_len  = (const int*)d_in[1];
    const float* node_x   = (const float*)d_in[2];
    const float* node_w   = (const float*)d_in[3];
    const int*   gids     = (const int*)d_in[4];
    const float* pro      = (const float*)d_in[5];
    const float* W_in     = (const float*)d_in[6];
    const float* b_in     = (const float*)d_in[7];
    const float* W_pred   = (const float*)d_in[8];
    const float* b_pred   = (const float*)d_in[9];
    const float* W_extra  = (const float*)d_in[10];
    const float* b_extra  = (const float*)d_in[11];
    const float* W_hid    = (const float*)d_in[12];
    const float* b_hid    = (const float*)d_in[13];

    float* out = (float*)d_out;
    float* outputs = out + OUT_OUTPUTS;
    float* hidden  = out + OUT_HIDDEN;
    float* lg      = out + OUT_LG;     // scratch for scores, overwritten in-place

    float* ws = (float*)d_ws;
    float* hid_partial = ws + WS_HIDPART;
    float* tblV = ws + WS_TBLV;
    int*   tblG = (int*)(ws + WS_TBLG);

    main_kernel<<<NBLK, TPB, 0, stream>>>(src, src_len, W_in, b_in,
                                          node_x, W_pred, b_pred, node_w, gids,
                                          outputs, hid_partial, lg, tblV, tblG);

    finish_kernel<<<LGOUT_BLOCKS + B_DIM, 256, 0, stream>>>(tblV, tblG, lg, gids, node_w,
                                                            pro, W_extra, b_extra, W_hid,
                                                            b_hid, hid_partial, hidden);
}